// Round 8
// baseline (159.371 us; speedup 1.0000x reference)
//
#include <hip/hip_runtime.h>
#include <hip/hip_cooperative_groups.h>
#include <stdint.h>

#pragma clang fp contract(off)

namespace cg = cooperative_groups;

#define BB 4
#define NN 2000
#define GG 100
#define HIMG 1024
#define WIMG 1024
#define PPOS 66
#define PNEG 134
#define TT 200
#define MH 28
#define MW 28
#define CHUNK 250
#define GRID 512

// output offsets (floats): rois [B,200,4], ids [B,200], deltas [B,200,4], masks [B,200,28,28]
#define OFF_ROIS 0
#define OFF_IDS  (BB*TT*4)
#define OFF_DELT (BB*TT*4 + BB*TT)
#define OFF_MASK (BB*TT*4 + BB*TT + BB*TT*4)

// ws layout (float/int units)
#define WS_SCP(b)  ((b)*2048)            // 2000 floats: gated pos scores
#define WS_SCN(b)  (8192 + (b)*2048)     // 2000 floats: gated neg scores
#define WS_CNT     16384                 // ints: [b*4]=npos
#define WS_PIDX(b) (16512 + (b)*128)     // ints: pos slot -> prop idx
#define WS_ASG(b)  (18048 + (b)*128)     // ints: pos slot -> gt idx

// LDS carve offsets (bytes) — phase A/B layout
#define SH_SC0    0                       // float[2000]
#define SH_SC1    8000                    // float[2000]
#define SH_MLIST  16000                   // int[2000]
#define SH_CNT    24000                   // int[256]
#define SH_BASE   25024                   // int[256]
#define SH_FILL   26048                   // int[256]
#define SH_GT     27072                   // float4[100] (16B aligned)
#define SH_GID    28672                   // int[100]
#define SH_SPOS   29072                   // int[66]
#define SH_SNEG   29336                   // int[134]
#define SH_TOT    29872                   // int[2]
#define SH_BYTES  29952
// phase C layout (reuses same bytes; fenced by __syncthreads before overwrite)
#define SHC_IY0   0
#define SHC_IY1   112
#define SHC_IX0   224
#define SHC_IX1   336
#define SHC_FY    448
#define SHC_FX    560
#define SHC_BOX   672

__device__ __forceinline__ void tf2x32(uint32_t k0, uint32_t k1, uint32_t& x0, uint32_t& x1){
  uint32_t ks2 = k0 ^ k1 ^ 0x1BD11BDAu;
  x0 += k0; x1 += k1;
#define TFR(r) { x0 += x1; x1 = (x1 << r) | (x1 >> (32 - r)); x1 ^= x0; }
  TFR(13) TFR(15) TFR(26) TFR(6)
  x0 += k1;  x1 += ks2 + 1u;
  TFR(17) TFR(29) TFR(16) TFR(24)
  x0 += ks2; x1 += k0 + 2u;
  TFR(13) TFR(15) TFR(26) TFR(6)
  x0 += k0;  x1 += k1 + 3u;
  TFR(17) TFR(29) TFR(16) TFR(24)
  x0 += k1;  x1 += ks2 + 4u;
  TFR(13) TFR(15) TFR(26) TFR(6)
  x0 += ks2; x1 += k0 + 5u;
#undef TFR
}

__device__ __forceinline__ float u01(uint32_t b){
  return __uint_as_float((b >> 9) | 0x3f800000u) - 1.0f;
}

__device__ __forceinline__ void img_keys(int b, uint32_t& k1a, uint32_t& k1b,
                                         uint32_t& k2a, uint32_t& k2b){
  uint32_t ia = 0u, ib = (uint32_t)b;
  tf2x32(0u, 42u, ia, ib);
  uint32_t a0 = 0u, c0 = 0u; tf2x32(ia, ib, a0, c0);
  uint32_t a1 = 0u, c1 = 1u; tf2x32(ia, ib, a1, c1);
  k1a = a0; k1b = c0; k2a = a1; k2b = c1;
}

__device__ __forceinline__ float iou2(float py1, float px1, float py2, float px2,
                                      float gy1, float gx1, float gy2, float gx2){
  float y1 = fmaxf(py1, gy1);
  float x1 = fmaxf(px1, gx1);
  float y2 = fminf(py2, gy2);
  float x2 = fminf(px2, gx2);
  float inter = fmaxf(x2 - x1, 0.0f) * fmaxf(y2 - y1, 0.0f);
  float a1 = (py2 - py1) * (px2 - px1);
  float a2 = (gy2 - gy1) * (gx2 - gx1);
  return inter / (a1 + a2 - inter);
}

__global__ __launch_bounds__(256, 2) void dtl_all(
    const float* __restrict__ props, const int* __restrict__ gids,
    const float* __restrict__ gboxes, const unsigned char* __restrict__ gmask,
    float* __restrict__ out, float* __restrict__ wsF, int* __restrict__ wsI)
{
  cg::grid_group grid = cg::this_grid();
  __shared__ __align__(16) unsigned char shB[SH_BYTES];
  const int blk = blockIdx.x;
  const int t = threadIdx.x;
  const int lane = t & 63, wave = t >> 6;

  float4* sGt  = (float4*)(shB + SH_GT);
  int*    sGid = (int*)(shB + SH_GID);

  // ---------------- phase A: eligibility + gated scores (blocks 0..31) ----------------
  if (blk < 32){
    const int cx = blk & 7, b = blk >> 3;
    if (t < GG){
      sGt[t]  = ((const float4*)(gboxes + b*GG*4))[t];
      sGid[t] = gids[b*GG + t];
    }
    __syncthreads();
    const int i = cx*CHUNK + t;
    if (t < CHUNK && i < NN){
      const float4 p = ((const float4*)(props + b*NN*4))[i];
      float best = -1.0f, cbest = -1.0f;
      for (int g = 0; g < GG; ++g){
        float4 gb = sGt[g];
        float v = iou2(p.x, p.y, p.z, p.w, gb.x, gb.y, gb.z, gb.w);
        int id = sGid[g];
        if (id > 0) best = fmaxf(best, v);
        else if (id < 0) cbest = fmaxf(cbest, v);
      }
      bool noc  = cbest < 1e-3f;
      bool posb = best >= 0.5f;
      bool negb = (best < 0.5f) && noc;
      uint32_t k1a, k1b, k2a, k2b;
      img_keys(b, k1a, k1b, k2a, k2b);
      uint32_t a = 0u, c = (uint32_t)i;
      tf2x32(k1a, k1b, a, c);
      uint32_t a2 = 0u, c2 = (uint32_t)i;
      tf2x32(k2a, k2b, a2, c2);
      wsF[WS_SCP(b) + i] = posb ? u01(a ^ c)   : -1.0f;
      wsF[WS_SCN(b) + i] = negb ? u01(a2 ^ c2) : -1.0f;
    }
  }
  grid.sync();

  // ---------------- phase B: bucket-rank top-k + emit (blocks 0..3) ----------------
  if (blk < BB){
    const int b = blk;
    float* sSc0  = (float*)(shB + SH_SC0);
    float* sSc1  = (float*)(shB + SH_SC1);
    int*   mlist = (int*)(shB + SH_MLIST);
    int*   cnt   = (int*)(shB + SH_CNT);
    int*   base_ = (int*)(shB + SH_BASE);
    int*   fill  = (int*)(shB + SH_FILL);
    int*   slotPos = (int*)(shB + SH_SPOS);
    int*   slotNeg = (int*)(shB + SH_SNEG);
    int*   sTot  = (int*)(shB + SH_TOT);

    if (t < GG){
      sGt[t]  = ((const float4*)(gboxes + b*GG*4))[t];
      sGid[t] = gids[b*GG + t];
    }
    for (int j = t; j < NN/4; j += 256){
      ((float4*)sSc0)[j] = ((const float4*)(wsF + WS_SCP(b)))[j];
      ((float4*)sSc1)[j] = ((const float4*)(wsF + WS_SCN(b)))[j];
    }

    for (int a = 0; a < 2; ++a){
      const int cap = a ? PNEG : PPOS;
      const float* sc = a ? sSc1 : sSc0;
      cnt[t] = 0; fill[t] = 0;
      __syncthreads();                  // fences loads (first iter) + zeroing
      for (int i = t; i < NN; i += 256){
        float v = sc[i];
        if (v >= 0.0f){
          int k = min((int)(v*256.0f), 255);
          atomicAdd(&cnt[k], 1);
        }
      }
      __syncthreads();
      if (wave == 0){
        int c0 = cnt[lane*4+0], c1 = cnt[lane*4+1], c2 = cnt[lane*4+2], c3 = cnt[lane*4+3];
        int p0 = c0, p1 = p0+c1, p2 = p1+c2, p3 = p2+c3;
        int inc = p3;
        for (int off = 1; off < 64; off <<= 1){
          int v = __shfl_up(inc, off);
          if (lane >= off) inc += v;
        }
        int excl = inc - p3;
        base_[lane*4+0] = excl;
        base_[lane*4+1] = excl + p0;
        base_[lane*4+2] = excl + p1;
        base_[lane*4+3] = excl + p2;
        if (lane == 63) sTot[a] = inc;
      }
      __syncthreads();
      for (int i = t; i < NN; i += 256){
        float v = sc[i];
        if (v >= 0.0f){
          int k = min((int)(v*256.0f), 255);
          int pos = base_[k] + atomicAdd(&fill[k], 1);
          mlist[pos] = i;
        }
      }
      __syncthreads();
      const int tot = sTot[a];
      int* slotArr = a ? slotNeg : slotPos;
      for (int i = t; i < NN; i += 256){
        float v = sc[i];
        if (v >= 0.0f){
          int k = min((int)(v*256.0f), 255);
          int S = tot - base_[k] - cnt[k];
          if (S < cap){
            int wr = 0;
            const int s0 = base_[k], e0 = s0 + cnt[k];
            for (int m = s0; m < e0; ++m){
              int j = mlist[m];
              float vj = sc[j];
              wr += (int)((vj > v) | ((vj == v) & (j < i)));
            }
            int slot = S + wr;
            if (slot < cap) slotArr[slot] = i;
          }
        }
      }
      __syncthreads();
    }

    const int npos = min(sTot[0], PPOS);
    int tgt = (int)((float)npos / 0.33f) - npos;  // exact fp32 semantics of reference
    if (tgt < 0) tgt = 0;
    const int nneg = min(min(sTot[1], tgt), PNEG);
    if (t == 0) wsI[WS_CNT + b*4] = npos;

    const float* pb = props + b*NN*4;
    if (t < TT){
      float r0=0,r1=0,r2=0,r3=0, idv=0, d0=0,d1=0,d2=0,d3=0;
      if (t < PPOS){
        if (t < npos){
          int idx = slotPos[t];
          float4 p = ((const float4*)pb)[idx];
          float bestv = -2.0f; int bg = 0;
          for (int g = 0; g < GG; ++g){
            float4 gb = sGt[g];
            float v = (sGid[g] > 0) ? iou2(p.x,p.y,p.z,p.w, gb.x,gb.y,gb.z,gb.w) : -1.0f;
            if (v > bestv){ bestv = v; bg = g; }
          }
          float4 gt = sGt[bg];
          float h  = p.z - p.x,        w  = p.w - p.y;
          float cy = p.x + 0.5f*h,     cx = p.y + 0.5f*w;
          float gh = gt.z - gt.x,      gw = gt.w - gt.y;
          float gcy = gt.x + 0.5f*gh,  gcx = gt.y + 0.5f*gw;
          r0 = p.x; r1 = p.y; r2 = p.z; r3 = p.w;
          idv = (float)sGid[bg];
          d0 = ((gcy - cy) / h) / 0.1f;
          d1 = ((gcx - cx) / w) / 0.1f;
          d2 = logf(gh / h) / 0.2f;
          d3 = logf(gw / w) / 0.2f;
          wsI[WS_PIDX(b) + t] = idx;
          wsI[WS_ASG(b) + t]  = bg;
        }
      } else {
        int pn = t - PPOS;
        if (pn < nneg){
          int idx = slotNeg[pn];
          float4 p = ((const float4*)pb)[idx];
          r0 = p.x; r1 = p.y; r2 = p.z; r3 = p.w;
        }
      }
      float* ro = out + OFF_ROIS + (b*TT + t)*4;
      ro[0] = r0; ro[1] = r1; ro[2] = r2; ro[3] = r3;
      out[OFF_IDS + b*TT + t] = idv;
      float* de = out + OFF_DELT + (b*TT + t)*4;
      de[0] = d0; de[1] = d1; de[2] = d2; de[3] = d3;
    }
  }
  grid.sync();

  // ------- phase C: mask crop+resize / zero-fill (grid-stride over 800 slots) -------
  for (int s = blk; s < BB*TT; s += GRID){
    const int b = s / TT;
    const int p = s % TT;
    const int npos = wsI[WS_CNT + b*4];       // block-uniform
    float* mo = out + OFF_MASK + (size_t)s * (MH*MW);
    if (p >= npos){
      for (int pix = t; pix < MH*MW; pix += 256) mo[pix] = 0.0f;
      continue;                                // uniform branch — no divergent barrier
    }
    int*   iy0 = (int*)(shB + SHC_IY0);
    int*   iy1 = (int*)(shB + SHC_IY1);
    int*   ix0 = (int*)(shB + SHC_IX0);
    int*   ix1 = (int*)(shB + SHC_IX1);
    float* fy  = (float*)(shB + SHC_FY);
    float* fx  = (float*)(shB + SHC_FX);
    float* sbox= (float*)(shB + SHC_BOX);
    __syncthreads();   // all lanes done with prior LDS contents before overwrite
    if (t == 0){
      int idx = wsI[WS_PIDX(b) + p];
      sbox[0] = props[(b*NN + idx)*4 + 0];
      sbox[1] = props[(b*NN + idx)*4 + 1];
      sbox[2] = props[(b*NN + idx)*4 + 2];
      sbox[3] = props[(b*NN + idx)*4 + 3];
    }
    __syncthreads();
    if (t < MH){
      float y1 = sbox[0], y2 = sbox[2];
      float stepy = (y2 - y1) * 1023.0f / 27.0f;
      float ys = y1 * 1023.0f + (float)t * stepy;
      float y0f = floorf(ys);
      iy0[t] = (int)fminf(fmaxf(y0f, 0.0f), 1023.0f);
      iy1[t] = (int)fminf(fmaxf(y0f + 1.0f, 0.0f), 1023.0f);
      fy[t] = ys - y0f;
      float x1 = sbox[1], x2 = sbox[3];
      float stepx = (x2 - x1) * 1023.0f / 27.0f;
      float xs = x1 * 1023.0f + (float)t * stepx;
      float x0f = floorf(xs);
      ix0[t] = (int)fminf(fmaxf(x0f, 0.0f), 1023.0f);
      ix1[t] = (int)fminf(fmaxf(x0f + 1.0f, 0.0f), 1023.0f);
      fx[t] = xs - x0f;
    }
    __syncthreads();
    const int g = wsI[WS_ASG(b) + p];
    const unsigned char* mb = gmask + (size_t)b * HIMG * WIMG * GG + g;
    for (int pix = t; pix < MH*MW; pix += 256){
      int r = pix / MW, c = pix - r*MW;
      size_t ro0 = (size_t)iy0[r] * WIMG;
      size_t ro1 = (size_t)iy1[r] * WIMG;
      float v00 = mb[(ro0 + (size_t)ix0[c]) * GG] ? 1.0f : 0.0f;
      float v01 = mb[(ro0 + (size_t)ix1[c]) * GG] ? 1.0f : 0.0f;
      float v10 = mb[(ro1 + (size_t)ix0[c]) * GG] ? 1.0f : 0.0f;
      float v11 = mb[(ro1 + (size_t)ix1[c]) * GG] ? 1.0f : 0.0f;
      float fxx = fx[c], fyy = fy[r];
      float top = v00 * (1.0f - fxx) + v01 * fxx;
      float bot = v10 * (1.0f - fxx) + v11 * fxx;
      float val = top * (1.0f - fyy) + bot * fyy;
      mo[pix] = rintf(val);
    }
    __syncthreads();   // finish gathers before next iteration overwrites LDS
  }
}

extern "C" void kernel_launch(void* const* d_in, const int* in_sizes, int n_in,
                              void* d_out, int out_size, void* d_ws, size_t ws_size,
                              hipStream_t stream){
  const float* props  = (const float*)d_in[0];
  const int*   gids   = (const int*)d_in[1];
  const float* gboxes = (const float*)d_in[2];
  const unsigned char* gmask = (const unsigned char*)d_in[3];
  float* out = (float*)d_out;
  float* wsF = (float*)d_ws;
  int*   wsI = (int*)d_ws;

  void* args[] = { (void*)&props, (void*)&gids, (void*)&gboxes, (void*)&gmask,
                   (void*)&out, (void*)&wsF, (void*)&wsI };
  hipLaunchCooperativeKernel((const void*)dtl_all, dim3(GRID), dim3(256),
                             args, 0, stream);
}

// Round 9
// 64.051 us; speedup vs baseline: 2.4882x; 2.4882x over previous
//
#include <hip/hip_runtime.h>
#include <stdint.h>

#pragma clang fp contract(off)

#define BB 4
#define NN 2000
#define GG 100
#define HIMG 1024
#define WIMG 1024
#define PPOS 66
#define PNEG 134
#define TT 200
#define MH 28
#define MW 28
#define CHUNK 250
#define GRID 512
#define MAGIC 0x5EC7ED42

// output offsets (floats): rois [B,200,4], ids [B,200], deltas [B,200,4], masks [B,200,28,28]
#define OFF_ROIS 0
#define OFF_IDS  (BB*TT*4)
#define OFF_DELT (BB*TT*4 + BB*TT)
#define OFF_MASK (BB*TT*4 + BB*TT + BB*TT*4)

// ws layout (float/int units)
#define WS_SCP(b)  ((b)*2048)            // 2000 floats: gated pos scores
#define WS_SCN(b)  (8192 + (b)*2048)     // 2000 floats: gated neg scores
#define WS_CNT     16384                 // ints: [b*4]=npos
#define WS_PIDX(b) (16512 + (b)*128)     // ints: pos slot -> prop idx
#define WS_ASG(b)  (18048 + (b)*128)     // ints: pos slot -> gt idx
#define WS_SFLG    18560                 // ints: 32 score-chunk flags [b*8+cx]
#define WS_DFLG    18600                 // ints: 4 per-image done flags

// LDS carve offsets (bytes) — phase B layout
#define SH_SC0    0                       // float[2000]
#define SH_SC1    8000                    // float[2000]
#define SH_MLIST  16000                   // int[2000]
#define SH_CNT    24000                   // int[256]
#define SH_BASE   25024                   // int[256]
#define SH_FILL   26048                   // int[256]
#define SH_GT     27072                   // float4[100] (16B aligned)
#define SH_GID    28672                   // int[100]
#define SH_SPOS   29072                   // int[66]
#define SH_SNEG   29336                   // int[134]
#define SH_TOT    29872                   // int[2]
#define SH_BYTES  29952
// phase C layout (reuses same bytes; fenced by __syncthreads before overwrite)
#define SHC_IY0   0
#define SHC_IY1   112
#define SHC_IX0   224
#define SHC_IX1   336
#define SHC_FY    448
#define SHC_FX    560
#define SHC_BOX   672

__device__ __forceinline__ void tf2x32(uint32_t k0, uint32_t k1, uint32_t& x0, uint32_t& x1){
  uint32_t ks2 = k0 ^ k1 ^ 0x1BD11BDAu;
  x0 += k0; x1 += k1;
#define TFR(r) { x0 += x1; x1 = (x1 << r) | (x1 >> (32 - r)); x1 ^= x0; }
  TFR(13) TFR(15) TFR(26) TFR(6)
  x0 += k1;  x1 += ks2 + 1u;
  TFR(17) TFR(29) TFR(16) TFR(24)
  x0 += ks2; x1 += k0 + 2u;
  TFR(13) TFR(15) TFR(26) TFR(6)
  x0 += k0;  x1 += k1 + 3u;
  TFR(17) TFR(29) TFR(16) TFR(24)
  x0 += k1;  x1 += ks2 + 4u;
  TFR(13) TFR(15) TFR(26) TFR(6)
  x0 += ks2; x1 += k0 + 5u;
#undef TFR
}

__device__ __forceinline__ float u01(uint32_t b){
  return __uint_as_float((b >> 9) | 0x3f800000u) - 1.0f;
}

__device__ __forceinline__ void img_keys(int b, uint32_t& k1a, uint32_t& k1b,
                                         uint32_t& k2a, uint32_t& k2b){
  uint32_t ia = 0u, ib = (uint32_t)b;
  tf2x32(0u, 42u, ia, ib);
  uint32_t a0 = 0u, c0 = 0u; tf2x32(ia, ib, a0, c0);
  uint32_t a1 = 0u, c1 = 1u; tf2x32(ia, ib, a1, c1);
  k1a = a0; k1b = c0; k2a = a1; k2b = c1;
}

__device__ __forceinline__ float iou2(float py1, float px1, float py2, float px2,
                                      float gy1, float gx1, float gy2, float gx2){
  float y1 = fmaxf(py1, gy1);
  float x1 = fmaxf(px1, gx1);
  float y2 = fminf(py2, gy2);
  float x2 = fminf(px2, gx2);
  float inter = fmaxf(x2 - x1, 0.0f) * fmaxf(y2 - y1, 0.0f);
  float a1 = (py2 - py1) * (px2 - px1);
  float a2 = (gy2 - gy1) * (gx2 - gx1);
  return inter / (a1 + a2 - inter);
}

__global__ __launch_bounds__(256, 2) void dtl_all(
    const float* __restrict__ props, const int* __restrict__ gids,
    const float* __restrict__ gboxes, const unsigned char* __restrict__ gmask,
    float* __restrict__ out, float* __restrict__ wsF, int* __restrict__ wsI)
{
  __shared__ __align__(16) unsigned char shB[SH_BYTES];
  const int blk = blockIdx.x;
  const int t = threadIdx.x;
  const int lane = t & 63, wave = t >> 6;

  float4* sGt  = (float4*)(shB + SH_GT);
  int*    sGid = (int*)(shB + SH_GID);

  // ---------------- phase A: eligibility + gated scores (blocks 0..31) ----------------
  if (blk < 32){
    const int cx = blk & 7, b = blk >> 3;
    if (t < GG){
      sGt[t]  = ((const float4*)(gboxes + b*GG*4))[t];
      sGid[t] = gids[b*GG + t];
    }
    __syncthreads();
    const int i = cx*CHUNK + t;
    if (t < CHUNK && i < NN){
      const float4 p = ((const float4*)(props + b*NN*4))[i];
      float best = -1.0f, cbest = -1.0f;
      for (int g = 0; g < GG; ++g){
        float4 gb = sGt[g];
        float v = iou2(p.x, p.y, p.z, p.w, gb.x, gb.y, gb.z, gb.w);
        int id = sGid[g];
        if (id > 0) best = fmaxf(best, v);
        else if (id < 0) cbest = fmaxf(cbest, v);
      }
      bool noc  = cbest < 1e-3f;
      bool posb = best >= 0.5f;
      bool negb = (best < 0.5f) && noc;
      uint32_t k1a, k1b, k2a, k2b;
      img_keys(b, k1a, k1b, k2a, k2b);
      uint32_t a = 0u, c = (uint32_t)i;
      tf2x32(k1a, k1b, a, c);
      uint32_t a2 = 0u, c2 = (uint32_t)i;
      tf2x32(k2a, k2b, a2, c2);
      wsF[WS_SCP(b) + i] = posb ? u01(a ^ c)   : -1.0f;
      wsF[WS_SCN(b) + i] = negb ? u01(a2 ^ c2) : -1.0f;
    }
    __syncthreads();   // compiler drains vmcnt before barrier -> stores in L2
    if (t == 0){
      __threadfence();
      __hip_atomic_store(&wsI[WS_SFLG + blk], MAGIC, __ATOMIC_RELEASE,
                         __HIP_MEMORY_SCOPE_AGENT);
    }
  }

  // ---------------- phase B: bucket-rank top-k + emit (blocks 0..3) ----------------
  if (blk < BB){
    const int b = blk;
    float* sSc0  = (float*)(shB + SH_SC0);
    float* sSc1  = (float*)(shB + SH_SC1);
    int*   mlist = (int*)(shB + SH_MLIST);
    int*   cnt   = (int*)(shB + SH_CNT);
    int*   base_ = (int*)(shB + SH_BASE);
    int*   fill  = (int*)(shB + SH_FILL);
    int*   slotPos = (int*)(shB + SH_SPOS);
    int*   slotNeg = (int*)(shB + SH_SNEG);
    int*   sTot  = (int*)(shB + SH_TOT);

    // wait for this image's 8 score chunks
    if (t < 8){
      while (__hip_atomic_load(&wsI[WS_SFLG + b*8 + t], __ATOMIC_ACQUIRE,
                               __HIP_MEMORY_SCOPE_AGENT) != MAGIC)
        __builtin_amdgcn_s_sleep(2);
    }
    __syncthreads();

    if (t < GG){
      sGt[t]  = ((const float4*)(gboxes + b*GG*4))[t];
      sGid[t] = gids[b*GG + t];
    }
    for (int j = t; j < NN/4; j += 256){
      ((float4*)sSc0)[j] = ((const float4*)(wsF + WS_SCP(b)))[j];
      ((float4*)sSc1)[j] = ((const float4*)(wsF + WS_SCN(b)))[j];
    }

    for (int a = 0; a < 2; ++a){
      const int cap = a ? PNEG : PPOS;
      const float* sc = a ? sSc1 : sSc0;
      cnt[t] = 0; fill[t] = 0;
      __syncthreads();                  // fences loads (first iter) + zeroing
      for (int i = t; i < NN; i += 256){
        float v = sc[i];
        if (v >= 0.0f){
          int k = min((int)(v*256.0f), 255);
          atomicAdd(&cnt[k], 1);
        }
      }
      __syncthreads();
      if (wave == 0){
        int c0 = cnt[lane*4+0], c1 = cnt[lane*4+1], c2 = cnt[lane*4+2], c3 = cnt[lane*4+3];
        int p0 = c0, p1 = p0+c1, p2 = p1+c2, p3 = p2+c3;
        int inc = p3;
        for (int off = 1; off < 64; off <<= 1){
          int v = __shfl_up(inc, off);
          if (lane >= off) inc += v;
        }
        int excl = inc - p3;
        base_[lane*4+0] = excl;
        base_[lane*4+1] = excl + p0;
        base_[lane*4+2] = excl + p1;
        base_[lane*4+3] = excl + p2;
        if (lane == 63) sTot[a] = inc;
      }
      __syncthreads();
      for (int i = t; i < NN; i += 256){
        float v = sc[i];
        if (v >= 0.0f){
          int k = min((int)(v*256.0f), 255);
          int pos = base_[k] + atomicAdd(&fill[k], 1);
          mlist[pos] = i;
        }
      }
      __syncthreads();
      const int tot = sTot[a];
      int* slotArr = a ? slotNeg : slotPos;
      for (int i = t; i < NN; i += 256){
        float v = sc[i];
        if (v >= 0.0f){
          int k = min((int)(v*256.0f), 255);
          int S = tot - base_[k] - cnt[k];
          if (S < cap){
            int wr = 0;
            const int s0 = base_[k], e0 = s0 + cnt[k];
            for (int m = s0; m < e0; ++m){
              int j = mlist[m];
              float vj = sc[j];
              wr += (int)((vj > v) | ((vj == v) & (j < i)));
            }
            int slot = S + wr;
            if (slot < cap) slotArr[slot] = i;
          }
        }
      }
      __syncthreads();
    }

    const int npos = min(sTot[0], PPOS);
    int tgt = (int)((float)npos / 0.33f) - npos;  // exact fp32 semantics of reference
    if (tgt < 0) tgt = 0;
    const int nneg = min(min(sTot[1], tgt), PNEG);
    if (t == 0) wsI[WS_CNT + b*4] = npos;

    const float* pb = props + b*NN*4;
    if (t < TT){
      float r0=0,r1=0,r2=0,r3=0, idv=0, d0=0,d1=0,d2=0,d3=0;
      if (t < PPOS){
        if (t < npos){
          int idx = slotPos[t];
          float4 p = ((const float4*)pb)[idx];
          float bestv = -2.0f; int bg = 0;
          for (int g = 0; g < GG; ++g){
            float4 gb = sGt[g];
            float v = (sGid[g] > 0) ? iou2(p.x,p.y,p.z,p.w, gb.x,gb.y,gb.z,gb.w) : -1.0f;
            if (v > bestv){ bestv = v; bg = g; }
          }
          float4 gt = sGt[bg];
          float h  = p.z - p.x,        w  = p.w - p.y;
          float cy = p.x + 0.5f*h,     cx = p.y + 0.5f*w;
          float gh = gt.z - gt.x,      gw = gt.w - gt.y;
          float gcy = gt.x + 0.5f*gh,  gcx = gt.y + 0.5f*gw;
          r0 = p.x; r1 = p.y; r2 = p.z; r3 = p.w;
          idv = (float)sGid[bg];
          d0 = ((gcy - cy) / h) / 0.1f;
          d1 = ((gcx - cx) / w) / 0.1f;
          d2 = logf(gh / h) / 0.2f;
          d3 = logf(gw / w) / 0.2f;
          wsI[WS_PIDX(b) + t] = idx;
          wsI[WS_ASG(b) + t]  = bg;
        }
      } else {
        int pn = t - PPOS;
        if (pn < nneg){
          int idx = slotNeg[pn];
          float4 p = ((const float4*)pb)[idx];
          r0 = p.x; r1 = p.y; r2 = p.z; r3 = p.w;
        }
      }
      float* ro = out + OFF_ROIS + (b*TT + t)*4;
      ro[0] = r0; ro[1] = r1; ro[2] = r2; ro[3] = r3;
      out[OFF_IDS + b*TT + t] = idv;
      float* de = out + OFF_DELT + (b*TT + t)*4;
      de[0] = d0; de[1] = d1; de[2] = d2; de[3] = d3;
    }
    __syncthreads();   // drain all global writes to L2 before release
    if (t == 0){
      __threadfence();
      __hip_atomic_store(&wsI[WS_DFLG + b], MAGIC, __ATOMIC_RELEASE,
                         __HIP_MEMORY_SCOPE_AGENT);
    }
  }

  // ------- phase C: mask crop+resize / zero-fill (grid-stride over 800 slots) -------
  for (int s = blk; s < BB*TT; s += GRID){
    const int b = s / TT;
    const int p = s % TT;
    if (t == 0){
      while (__hip_atomic_load(&wsI[WS_DFLG + b], __ATOMIC_ACQUIRE,
                               __HIP_MEMORY_SCOPE_AGENT) != MAGIC)
        __builtin_amdgcn_s_sleep(2);
    }
    __syncthreads();                         // flag broadcast + LDS reuse fence
    const int npos = wsI[WS_CNT + b*4];      // block-uniform
    float* mo = out + OFF_MASK + (size_t)s * (MH*MW);
    if (p >= npos){
      for (int pix = t; pix < MH*MW; pix += 256) mo[pix] = 0.0f;
      continue;                              // uniform branch — no divergent barrier
    }
    int*   iy0 = (int*)(shB + SHC_IY0);
    int*   iy1 = (int*)(shB + SHC_IY1);
    int*   ix0 = (int*)(shB + SHC_IX0);
    int*   ix1 = (int*)(shB + SHC_IX1);
    float* fy  = (float*)(shB + SHC_FY);
    float* fx  = (float*)(shB + SHC_FX);
    float* sbox= (float*)(shB + SHC_BOX);
    if (t == 0){
      int idx = wsI[WS_PIDX(b) + p];
      sbox[0] = props[(b*NN + idx)*4 + 0];
      sbox[1] = props[(b*NN + idx)*4 + 1];
      sbox[2] = props[(b*NN + idx)*4 + 2];
      sbox[3] = props[(b*NN + idx)*4 + 3];
    }
    __syncthreads();
    if (t < MH){
      float y1 = sbox[0], y2 = sbox[2];
      float stepy = (y2 - y1) * 1023.0f / 27.0f;
      float ys = y1 * 1023.0f + (float)t * stepy;
      float y0f = floorf(ys);
      iy0[t] = (int)fminf(fmaxf(y0f, 0.0f), 1023.0f);
      iy1[t] = (int)fminf(fmaxf(y0f + 1.0f, 0.0f), 1023.0f);
      fy[t] = ys - y0f;
      float x1 = sbox[1], x2 = sbox[3];
      float stepx = (x2 - x1) * 1023.0f / 27.0f;
      float xs = x1 * 1023.0f + (float)t * stepx;
      float x0f = floorf(xs);
      ix0[t] = (int)fminf(fmaxf(x0f, 0.0f), 1023.0f);
      ix1[t] = (int)fminf(fmaxf(x0f + 1.0f, 0.0f), 1023.0f);
      fx[t] = xs - x0f;
    }
    __syncthreads();
    const int g = wsI[WS_ASG(b) + p];
    const unsigned char* mb = gmask + (size_t)b * HIMG * WIMG * GG + g;
    for (int pix = t; pix < MH*MW; pix += 256){
      int r = pix / MW, c = pix - r*MW;
      size_t ro0 = (size_t)iy0[r] * WIMG;
      size_t ro1 = (size_t)iy1[r] * WIMG;
      float v00 = mb[(ro0 + (size_t)ix0[c]) * GG] ? 1.0f : 0.0f;
      float v01 = mb[(ro0 + (size_t)ix1[c]) * GG] ? 1.0f : 0.0f;
      float v10 = mb[(ro1 + (size_t)ix0[c]) * GG] ? 1.0f : 0.0f;
      float v11 = mb[(ro1 + (size_t)ix1[c]) * GG] ? 1.0f : 0.0f;
      float fxx = fx[c], fyy = fy[r];
      float top = v00 * (1.0f - fxx) + v01 * fxx;
      float bot = v10 * (1.0f - fxx) + v11 * fxx;
      float val = top * (1.0f - fyy) + bot * fyy;
      mo[pix] = rintf(val);
    }
    __syncthreads();   // finish LDS reads before next iteration overwrites
  }
}

extern "C" void kernel_launch(void* const* d_in, const int* in_sizes, int n_in,
                              void* d_out, int out_size, void* d_ws, size_t ws_size,
                              hipStream_t stream){
  const float* props  = (const float*)d_in[0];
  const int*   gids   = (const int*)d_in[1];
  const float* gboxes = (const float*)d_in[2];
  const unsigned char* gmask = (const unsigned char*)d_in[3];
  float* out = (float*)d_out;
  float* wsF = (float*)d_ws;
  int*   wsI = (int*)d_ws;

  dtl_all<<<GRID, 256, 0, stream>>>(props, gids, gboxes, gmask, out, wsF, wsI);
}

// Round 11
// 52.315 us; speedup vs baseline: 3.0464x; 1.2243x over previous
//
#include <hip/hip_runtime.h>
#include <stdint.h>

#pragma clang fp contract(off)

#define BB 4
#define NN 2000
#define GG 100
#define HIMG 1024
#define WIMG 1024
#define PPOS 66
#define PNEG 134
#define TT 200
#define MH 28
#define MW 28
#define NCHUNK 16
#define CHUNK 125
#define ABLK (BB*NCHUNK)     // 64 score blocks
#define GRID 512
#define MAGIC 0x5EC7ED42

// output offsets (floats): rois [B,200,4], ids [B,200], deltas [B,200,4], masks [B,200,28,28]
#define OFF_ROIS 0
#define OFF_IDS  (BB*TT*4)
#define OFF_DELT (BB*TT*4 + BB*TT)
#define OFF_MASK (BB*TT*4 + BB*TT + BB*TT*4)

// ws layout (float/int units)
#define WS_SCP(b)  ((b)*2048)            // 2000 floats: gated pos scores
#define WS_SCN(b)  (8192 + (b)*2048)     // 2000 floats: gated neg scores
#define WS_CNT     16384                 // ints: [b*4]=npos
#define WS_PIDX(b) (16512 + (b)*128)     // ints: pos slot -> prop idx
#define WS_ASG(b)  (18048 + (b)*128)     // ints: pos slot -> gt idx
#define WS_SFLG    18560                 // ints: 64 score-chunk flags [b*16+cx]
#define WS_DFLG    18624                 // ints: 4 per-image pos-done flags

// LDS carve offsets (bytes)
#define SH_SC0    0                       // float[2000] (pos or neg scores)
#define SH_MLIST  16000                   // int[2000]
#define SH_CNT    24000                   // int[256]
#define SH_BASE   25024                   // int[256]
#define SH_FILL   26048                   // int[256]
#define SH_GT     27072                   // float4[100] (16B aligned)
#define SH_GID    28672                   // int[100]
#define SH_SPOS   29072                   // int[66]
#define SH_SNEG   29336                   // int[134]
#define SH_TOT    29872                   // int[2]
#define SH_BYTES  29952
// phase C layout (reuses same bytes; fenced before overwrite)
#define SHC_IY0   0
#define SHC_IY1   112
#define SHC_IX0   224
#define SHC_IX1   336
#define SHC_FY    448
#define SHC_FX    560
#define SHC_BOX   672

__device__ __forceinline__ void tf2x32(uint32_t k0, uint32_t k1, uint32_t& x0, uint32_t& x1){
  uint32_t ks2 = k0 ^ k1 ^ 0x1BD11BDAu;
  x0 += k0; x1 += k1;
#define TFR(r) { x0 += x1; x1 = (x1 << r) | (x1 >> (32 - r)); x1 ^= x0; }
  TFR(13) TFR(15) TFR(26) TFR(6)
  x0 += k1;  x1 += ks2 + 1u;
  TFR(17) TFR(29) TFR(16) TFR(24)
  x0 += ks2; x1 += k0 + 2u;
  TFR(13) TFR(15) TFR(26) TFR(6)
  x0 += k0;  x1 += k1 + 3u;
  TFR(17) TFR(29) TFR(16) TFR(24)
  x0 += k1;  x1 += ks2 + 4u;
  TFR(13) TFR(15) TFR(26) TFR(6)
  x0 += ks2; x1 += k0 + 5u;
#undef TFR
}

__device__ __forceinline__ float u01(uint32_t b){
  return __uint_as_float((b >> 9) | 0x3f800000u) - 1.0f;
}

__device__ __forceinline__ void img_keys(int b, uint32_t& k1a, uint32_t& k1b,
                                         uint32_t& k2a, uint32_t& k2b){
  uint32_t ia = 0u, ib = (uint32_t)b;
  tf2x32(0u, 42u, ia, ib);
  uint32_t a0 = 0u, c0 = 0u; tf2x32(ia, ib, a0, c0);
  uint32_t a1 = 0u, c1 = 1u; tf2x32(ia, ib, a1, c1);
  k1a = a0; k1b = c0; k2a = a1; k2b = c1;
}

__device__ __forceinline__ float iou2(float py1, float px1, float py2, float px2,
                                      float gy1, float gx1, float gy2, float gx2){
  float y1 = fmaxf(py1, gy1);
  float x1 = fmaxf(px1, gx1);
  float y2 = fminf(py2, gy2);
  float x2 = fminf(px2, gx2);
  float inter = fmaxf(x2 - x1, 0.0f) * fmaxf(y2 - y1, 0.0f);
  float a1 = (py2 - py1) * (px2 - px1);
  float a2 = (gy2 - gy1) * (gx2 - gx1);
  return inter / (a1 + a2 - inter);
}

// exact top-k via bucket-rank; returns eligible count. Uses shared cnt/base_/fill/mlist/sTot.
__device__ __forceinline__ int bucket_select(
    const float* sc, int cap, int* slotArr,
    int* cnt, int* base_, int* fill, int* mlist, int* sTot,
    int t, int lane, int wave)
{
  cnt[t] = 0; fill[t] = 0;
  __syncthreads();                 // also fences caller's LDS score staging
  for (int i = t; i < NN; i += 256){
    float v = sc[i];
    if (v >= 0.0f){
      int k = min((int)(v*256.0f), 255);
      atomicAdd(&cnt[k], 1);
    }
  }
  __syncthreads();
  if (wave == 0){
    int c0 = cnt[lane*4+0], c1 = cnt[lane*4+1], c2 = cnt[lane*4+2], c3 = cnt[lane*4+3];
    int p0 = c0, p1 = p0+c1, p2 = p1+c2, p3 = p2+c3;
    int inc = p3;
    for (int off = 1; off < 64; off <<= 1){
      int v = __shfl_up(inc, off);
      if (lane >= off) inc += v;
    }
    int excl = inc - p3;
    base_[lane*4+0] = excl;
    base_[lane*4+1] = excl + p0;
    base_[lane*4+2] = excl + p1;
    base_[lane*4+3] = excl + p2;
    if (lane == 63) sTot[0] = inc;
  }
  __syncthreads();
  const int tot = sTot[0];
  // scatter only qualifying buckets (those possibly holding top-cap members)
  for (int i = t; i < NN; i += 256){
    float v = sc[i];
    if (v >= 0.0f){
      int k = min((int)(v*256.0f), 255);
      if (tot - base_[k] - cnt[k] < cap){
        int pos = base_[k] + atomicAdd(&fill[k], 1);
        mlist[pos] = i;
      }
    }
  }
  __syncthreads();
  for (int i = t; i < NN; i += 256){
    float v = sc[i];
    if (v >= 0.0f){
      int k = min((int)(v*256.0f), 255);
      int S = tot - base_[k] - cnt[k];
      if (S < cap){
        int wr = 0;
        const int s0 = base_[k], e0 = s0 + cnt[k];
        for (int m = s0; m < e0; ++m){
          int j = mlist[m];
          float vj = sc[j];
          wr += (int)((vj > v) | ((vj == v) & (j < i)));
        }
        int slot = S + wr;
        if (slot < cap) slotArr[slot] = i;
      }
    }
  }
  __syncthreads();
  return tot;
}

__global__ __launch_bounds__(256, 2) void dtl_all(
    const float* __restrict__ props, const int* __restrict__ gids,
    const float* __restrict__ gboxes, const unsigned char* __restrict__ gmask,
    float* __restrict__ out, float* __restrict__ wsF, int* __restrict__ wsI)
{
  __shared__ __align__(16) unsigned char shB[SH_BYTES];
  const int blk = blockIdx.x;
  const int t = threadIdx.x;
  const int lane = t & 63, wave = t >> 6;

  float4* sGt  = (float4*)(shB + SH_GT);
  int*    sGid = (int*)(shB + SH_GID);
  float*  sSc  = (float*)(shB + SH_SC0);
  int*    mlist= (int*)(shB + SH_MLIST);
  int*    cnt  = (int*)(shB + SH_CNT);
  int*    base_= (int*)(shB + SH_BASE);
  int*    fill = (int*)(shB + SH_FILL);
  int*    slotPos = (int*)(shB + SH_SPOS);
  int*    slotNeg = (int*)(shB + SH_SNEG);
  int*    sTot = (int*)(shB + SH_TOT);

  // ---------------- phase A: eligibility + gated scores (blocks 0..63) ----------------
  if (blk < ABLK){
    const int cx = blk & (NCHUNK-1), b = blk >> 4;
    if (t < GG){
      sGt[t]  = ((const float4*)(gboxes + b*GG*4))[t];
      sGid[t] = gids[b*GG + t];
    }
    __syncthreads();
    const int i = cx*CHUNK + t;
    if (t < CHUNK){
      const float4 p = ((const float4*)(props + b*NN*4))[i];
      float best = -1.0f, cbest = -1.0f;
      for (int g = 0; g < GG; ++g){
        float4 gb = sGt[g];
        float v = iou2(p.x, p.y, p.z, p.w, gb.x, gb.y, gb.z, gb.w);
        int id = sGid[g];
        if (id > 0) best = fmaxf(best, v);
        else if (id < 0) cbest = fmaxf(cbest, v);
      }
      bool noc  = cbest < 1e-3f;
      bool posb = best >= 0.5f;
      bool negb = (best < 0.5f) && noc;
      uint32_t k1a, k1b, k2a, k2b;
      img_keys(b, k1a, k1b, k2a, k2b);
      uint32_t a = 0u, c = (uint32_t)i;
      tf2x32(k1a, k1b, a, c);
      uint32_t a2 = 0u, c2 = (uint32_t)i;
      tf2x32(k2a, k2b, a2, c2);
      wsF[WS_SCP(b) + i] = posb ? u01(a ^ c)   : -1.0f;
      wsF[WS_SCN(b) + i] = negb ? u01(a2 ^ c2) : -1.0f;
    }
    __syncthreads();   // drains vmcnt -> stores in L2
    if (t == 0){
      __threadfence();
      __hip_atomic_store(&wsI[WS_SFLG + blk], MAGIC, __ATOMIC_RELEASE,
                         __HIP_MEMORY_SCOPE_AGENT);
    }
  }

  // -------- phase B-pos: pos top-k + emit + EARLY release (blocks 0..3) --------
  if (blk < BB){
    const int b = blk;
    if (t < NCHUNK){
      while (__hip_atomic_load(&wsI[WS_SFLG + b*NCHUNK + t], __ATOMIC_ACQUIRE,
                               __HIP_MEMORY_SCOPE_AGENT) != MAGIC)
        __builtin_amdgcn_s_sleep(2);
    }
    __syncthreads();
    if (t < GG){
      sGt[t]  = ((const float4*)(gboxes + b*GG*4))[t];
      sGid[t] = gids[b*GG + t];
    }
    for (int j = t; j < NN/4; j += 256)
      ((float4*)sSc)[j] = ((const float4*)(wsF + WS_SCP(b)))[j];

    int tot = bucket_select(sSc, PPOS, slotPos, cnt, base_, fill, mlist, sTot,
                            t, lane, wave);
    const int npos = min(tot, PPOS);
    if (t == 0) wsI[WS_CNT + b*4] = npos;

    const float* pb = props + b*NN*4;
    if (t < TT){
      float idv = 0, d0=0, d1=0, d2=0, d3=0;
      if (t < PPOS){
        float r0=0, r1=0, r2=0, r3=0;
        if (t < npos){
          int idx = slotPos[t];
          float4 p = ((const float4*)pb)[idx];
          float bestv = -2.0f; int bg = 0;
          for (int g = 0; g < GG; ++g){
            float4 gb = sGt[g];
            float v = (sGid[g] > 0) ? iou2(p.x,p.y,p.z,p.w, gb.x,gb.y,gb.z,gb.w) : -1.0f;
            if (v > bestv){ bestv = v; bg = g; }
          }
          float4 gt = sGt[bg];
          float h  = p.z - p.x,        w  = p.w - p.y;
          float cy = p.x + 0.5f*h,     cx = p.y + 0.5f*w;
          float gh = gt.z - gt.x,      gw = gt.w - gt.y;
          float gcy = gt.x + 0.5f*gh,  gcx = gt.y + 0.5f*gw;
          r0 = p.x; r1 = p.y; r2 = p.z; r3 = p.w;
          idv = (float)sGid[bg];
          d0 = ((gcy - cy) / h) / 0.1f;
          d1 = ((gcx - cx) / w) / 0.1f;
          d2 = logf(gh / h) / 0.2f;
          d3 = logf(gw / w) / 0.2f;
          wsI[WS_PIDX(b) + t] = idx;
          wsI[WS_ASG(b) + t]  = bg;
        }
        float* ro = out + OFF_ROIS + (b*TT + t)*4;
        ro[0] = r0; ro[1] = r1; ro[2] = r2; ro[3] = r3;
      }
      out[OFF_IDS + b*TT + t] = idv;
      float* de = out + OFF_DELT + (b*TT + t)*4;
      de[0] = d0; de[1] = d1; de[2] = d2; de[3] = d3;
    }
    __syncthreads();   // drain global writes before release
    if (t == 0){
      __threadfence();
      __hip_atomic_store(&wsI[WS_DFLG + b], MAGIC, __ATOMIC_RELEASE,
                         __HIP_MEMORY_SCOPE_AGENT);
    }
  }

  // -------- phase B-neg: neg top-k + rois emit (blocks 4..7, concurrent) --------
  if (blk >= BB && blk < 2*BB){
    const int b = blk - BB;
    if (t < NCHUNK){
      while (__hip_atomic_load(&wsI[WS_SFLG + b*NCHUNK + t], __ATOMIC_ACQUIRE,
                               __HIP_MEMORY_SCOPE_AGENT) != MAGIC)
        __builtin_amdgcn_s_sleep(2);
    }
    __syncthreads();
    for (int j = t; j < NN/4; j += 256)
      ((float4*)sSc)[j] = ((const float4*)(wsF + WS_SCN(b)))[j];

    int tot1 = bucket_select(sSc, PNEG, slotNeg, cnt, base_, fill, mlist, sTot,
                             t, lane, wave);
    // need npos only now (pos block releases early)
    if (t == 0){
      while (__hip_atomic_load(&wsI[WS_DFLG + b], __ATOMIC_ACQUIRE,
                               __HIP_MEMORY_SCOPE_AGENT) != MAGIC)
        __builtin_amdgcn_s_sleep(2);
    }
    __syncthreads();
    const int npos = wsI[WS_CNT + b*4];
    int tgt = (int)((float)npos / 0.33f) - npos;   // exact fp32 semantics
    if (tgt < 0) tgt = 0;
    const int nneg = min(min(tot1, tgt), PNEG);
    if (t < PNEG){
      float r0=0, r1=0, r2=0, r3=0;
      if (t < nneg){
        int idx = slotNeg[t];
        float4 p = ((const float4*)(props + b*NN*4))[idx];
        r0 = p.x; r1 = p.y; r2 = p.z; r3 = p.w;
      }
      float* ro = out + OFF_ROIS + (b*TT + PPOS + t)*4;
      ro[0] = r0; ro[1] = r1; ro[2] = r2; ro[3] = r3;
    }
  }

  // ------- phase C: masks. reverse slot map keeps crops off A/B blocks -------
  for (int s = (BB*TT - 1) - blk; s >= 0; s -= GRID){
    const int b = s / TT;
    const int p = s % TT;
    float* mo = out + OFF_MASK + (size_t)s * (MH*MW);
    if (p >= PPOS){            // always zero — no dependency, runs during A/B
      for (int pix = t; pix < MH*MW; pix += 256) mo[pix] = 0.0f;
      continue;
    }
    if (t == 0){
      while (__hip_atomic_load(&wsI[WS_DFLG + b], __ATOMIC_ACQUIRE,
                               __HIP_MEMORY_SCOPE_AGENT) != MAGIC)
        __builtin_amdgcn_s_sleep(2);
    }
    __syncthreads();                        // flag broadcast + LDS reuse fence
    const int npos = wsI[WS_CNT + b*4];     // block-uniform
    if (p >= npos){
      for (int pix = t; pix < MH*MW; pix += 256) mo[pix] = 0.0f;
      continue;
    }
    int*   iy0 = (int*)(shB + SHC_IY0);
    int*   iy1 = (int*)(shB + SHC_IY1);
    int*   ix0 = (int*)(shB + SHC_IX0);
    int*   ix1 = (int*)(shB + SHC_IX1);
    float* fy  = (float*)(shB + SHC_FY);
    float* fx  = (float*)(shB + SHC_FX);
    float* sbox= (float*)(shB + SHC_BOX);
    if (t == 0){
      int idx = wsI[WS_PIDX(b) + p];
      sbox[0] = props[(b*NN + idx)*4 + 0];
      sbox[1] = props[(b*NN + idx)*4 + 1];
      sbox[2] = props[(b*NN + idx)*4 + 2];
      sbox[3] = props[(b*NN + idx)*4 + 3];
    }
    __syncthreads();
    if (t < MH){
      float y1 = sbox[0], y2 = sbox[2];
      float stepy = (y2 - y1) * 1023.0f / 27.0f;
      float ys = y1 * 1023.0f + (float)t * stepy;
      float y0f = floorf(ys);
      iy0[t] = (int)fminf(fmaxf(y0f, 0.0f), 1023.0f);
      iy1[t] = (int)fminf(fmaxf(y0f + 1.0f, 0.0f), 1023.0f);
      fy[t] = ys - y0f;
      float x1 = sbox[1], x2 = sbox[3];
      float stepx = (x2 - x1) * 1023.0f / 27.0f;
      float xs = x1 * 1023.0f + (float)t * stepx;
      float x0f = floorf(xs);
      ix0[t] = (int)fminf(fmaxf(x0f, 0.0f), 1023.0f);
      ix1[t] = (int)fminf(fmaxf(x0f + 1.0f, 0.0f), 1023.0f);
      fx[t] = xs - x0f;
    }
    __syncthreads();
    const int g = wsI[WS_ASG(b) + p];
    const unsigned char* mb = gmask + (size_t)b * HIMG * WIMG * GG + g;
    for (int pix = t; pix < MH*MW; pix += 256){
      int r = pix / MW, c = pix - r*MW;
      size_t ro0 = (size_t)iy0[r] * WIMG;
      size_t ro1 = (size_t)iy1[r] * WIMG;
      float v00 = mb[(ro0 + (size_t)ix0[c]) * GG] ? 1.0f : 0.0f;
      float v01 = mb[(ro0 + (size_t)ix1[c]) * GG] ? 1.0f : 0.0f;
      float v10 = mb[(ro1 + (size_t)ix0[c]) * GG] ? 1.0f : 0.0f;
      float v11 = mb[(ro1 + (size_t)ix1[c]) * GG] ? 1.0f : 0.0f;
      float fxx = fx[c], fyy = fy[r];
      float top = v00 * (1.0f - fxx) + v01 * fxx;
      float bot = v10 * (1.0f - fxx) + v11 * fxx;
      float val = top * (1.0f - fyy) + bot * fyy;
      mo[pix] = rintf(val);
    }
    __syncthreads();   // finish LDS reads before next iteration overwrites
  }
}

extern "C" void kernel_launch(void* const* d_in, const int* in_sizes, int n_in,
                              void* d_out, int out_size, void* d_ws, size_t ws_size,
                              hipStream_t stream){
  const float* props  = (const float*)d_in[0];
  const int*   gids   = (const int*)d_in[1];
  const float* gboxes = (const float*)d_in[2];
  const unsigned char* gmask = (const unsigned char*)d_in[3];
  float* out = (float*)d_out;
  float* wsF = (float*)d_ws;
  int*   wsI = (int*)d_ws;

  dtl_all<<<GRID, 256, 0, stream>>>(props, gids, gboxes, gmask, out, wsF, wsI);
}